// Round 4
// baseline (2147.774 us; speedup 1.0000x reference)
//
#include <hip/hip_runtime.h>
#include <hip/hip_bf16.h>

#define H 128
#define FOURH 512
#define BATCH 64
#define SEQ 2048
#define TC SEQ
#define NCHUNK 128                 // 2048 / 16 steps per chunk
#define RSLOT 256                  // G-ring depth in steps (16 chunks)
#define GSTRIDE (BATCH * FOURH)    // floats per ring slot
#define D1 4                       // worker G1 delay (chunks) behind its G0 index

typedef _Float16 half8 __attribute__((ext_vector_type(8)));
typedef float f32x4 __attribute__((ext_vector_type(4)));

// ---- prep: transpose Wih0 -> [K][512], fp16 Wih1, sum biases, zero flags ----
__global__ void prep_kernel(const float* __restrict__ Wih0,
                            const float* __restrict__ bih0, const float* __restrict__ bhh0,
                            const float* __restrict__ bih1, const float* __restrict__ bhh1,
                            const float* __restrict__ Wih1,
                            float* __restrict__ Wt0,
                            float* __restrict__ b0, float* __restrict__ b1,
                            _Float16* __restrict__ wt1h,
                            int* __restrict__ flags) {
    int id = blockIdx.x * 256 + threadIdx.x;
    const int N0 = 256 * 512;
    if (id < N0) {
        int k = id >> 9, n = id & 511;
        Wt0[id] = Wih0[n * 256 + k];
    } else if (id < N0 + 512) {
        int i = id - N0;
        b0[i] = bih0[i] + bhh0[i];
    } else if (id < N0 + 1024) {
        int i = id - (N0 + 512);
        b1[i] = bih1[i] + bhh1[i];
    } else if (id < N0 + 1024 + 65536) {
        int i = id - (N0 + 1024);
        wt1h[i] = (_Float16)Wih1[i];          // same RNE rounding the consumer used
    } else if (id < N0 + 1024 + 65536 + 272) {
        flags[id - (N0 + 1024 + 65536)] = 0;
    }
}

// ---------------- fused persistent kernel ----------------
__device__ __forceinline__ float sigmoid_f(float x) {
    return __builtin_amdgcn_rcpf(1.f + __expf(-x));
}
__device__ __forceinline__ float tanh_f(float x) {
    return 1.f - 2.f * __builtin_amdgcn_rcpf(__expf(2.f * x) + 1.f);
}

// Light barrier: LDS handoff only. Global loads/stores stay in flight across it.
#define LDS_BARRIER()                                                \
    do {                                                             \
        asm volatile("s_waitcnt lgkmcnt(0)" ::: "memory");           \
        __builtin_amdgcn_s_barrier();                                \
        __builtin_amdgcn_sched_barrier(0);                           \
    } while (0)

#define BM 128
#define BN 128
#define BK 32

// 240 blocks x 512 threads:
//   blocks 0-7   producer: layer-0 scan (16 MFMA/wave/step), reads G0 ring.
//   blocks 8-15  consumer: layer-1 recurrent-only scan (16 MFMA/wave/step),
//                reads G1 ring (input projection pre-computed by workers).
//   blocks 16-239 workers (7 classes x 32 sub-blocks). Per round:
//                G0(idx): fp32 scalar GEMM chunk of x@Wih0^T+b0 into G0 ring
//                         (ring-space gated on prodF, bit-identical to R3);
//                G1(idx-D1): fp16-MFMA chunk of h1@Wih1^T+b1 into G1 ring
//                         (gated on prodF for data, consF for ring space) --
//                         exact replay of the old consumer's input-MFMA chain,
//                         so layer-1 numerics are bit-identical.
// Rings are 256 steps (33.5 MB each) -> whole pipeline working set ~100 MB,
// L3-resident; write->read gaps are bounded by the flow control.
// Gate graph is acyclic with >=13-chunk lag margins (no deadlock).
__global__ __launch_bounds__(512, 2) void lstm_fused_kernel(
    const float* __restrict__ x,      // [64][T][256]
    const float* __restrict__ Wt0,    // [256][512] transposed Wih0
    const float* __restrict__ b0sum,  // [512] summed layer-0 biases
    float* __restrict__ gring,        // [256][64][512] G0 ring (t-major slots)
    const float* __restrict__ Whh0,   // [512][128]
    const _Float16* __restrict__ wt1h,// [512][128] fp16 Wih1
    const float* __restrict__ Whh1,   // [512][128]
    const float* __restrict__ b1,     // [512] summed layer-1 biases
    _Float16* __restrict__ h1p,       // [T][64][128] fp16 layer-0 hidden
    float* __restrict__ g1r,          // [256][64][512] G1 ring (t-major slots)
    float* __restrict__ out,          // [64][T][128] fp32 layer-1 hidden
    int* __restrict__ flags)          // [8]prodF [8]consF [128]chunkDone [128]g1Done
{
    const int tid = threadIdx.x;

    int* prodF     = flags;
    int* consF     = flags + 8;
    int* chunkDone = flags + 16;
    int* g1Done    = flags + 144;

    __shared__ _Float16 hbuf[2][8][136];   // scan recurrent h, fp16, dbuf
    __shared__ float As[BK][BM + 4];       // worker G0 staging
    __shared__ float Bs[BK][BN];

    if (blockIdx.x >= 16) {
        // ================= workers =================
        const int j   = blockIdx.x - 16;    // 0..223
        const int sub = j & 31;             // sub-block within chunk
        const int cls = j >> 5;             // chunk class 0..6
        const int by  = sub >> 2;           // row-block == batch group 0..7
        const int bx  = sub & 3;            // col-block (128 of 512)
        const int n0  = bx * BN;
        const int tm  = tid >> 5;           // 0..15
        const int tn  = tid & 31;           // 0..31
        // G1 (MFMA) lane mapping
        const int wv  = tid >> 6;           // wave 0..7 -> batch within group
        const int l   = tid & 63;
        const int li  = l & 15;
        const int q   = l >> 4;
        const int gb1 = 8 * by + wv;        // batch for this wave's G1 rows

        int ar[2], aq[2], bkk[2], bq[2];
#pragma unroll
        for (int l2 = 0; l2 < 2; ++l2) {
            int fidx = tid + l2 * 512;
            ar[l2] = fidx >> 3; aq[l2] = fidx & 7;
            bkk[l2] = fidx >> 5; bq[l2] = fidx & 31;
        }
        float4 bvg = *(const float4*)&b0sum[n0 + tn * 4];
        float bv1g[8];
#pragma unroll
        for (int ct = 0; ct < 8; ++ct) bv1g[ct] = b1[n0 + ct * 16 + li];

        for (int idx = cls; idx < NCHUNK + D1; idx += 7) {
            if (idx < NCHUNK) {
                // ---- G0 chunk idx (fp32 scalar GEMM, bit-identical) ----
                if (idx >= 16) {          // ring-space gate (256-step ring)
                    if (tid == 0) {
                        while (__hip_atomic_load(&prodF[by], __ATOMIC_RELAXED,
                                                 __HIP_MEMORY_SCOPE_AGENT) < 16 * (idx - 15))
                            __builtin_amdgcn_s_sleep(4);
                    }
                    __syncthreads();
                }
                const float* aptr[2];
#pragma unroll
                for (int l2 = 0; l2 < 2; ++l2) {
                    int rl = by * BM + ar[l2];
                    int b = rl >> 4;
                    int t = idx * 16 + (rl & 15);
                    aptr[l2] = x + ((size_t)b * SEQ + t) * 256 + aq[l2] * 4;
                }
                float acc[2][4][4];
#pragma unroll
                for (int rh = 0; rh < 2; ++rh)
#pragma unroll
                    for (int i = 0; i < 4; ++i)
#pragma unroll
                        for (int jj = 0; jj < 4; ++jj) acc[rh][i][jj] = 0.f;

                for (int k0 = 0; k0 < 256; k0 += BK) {
                    __syncthreads();
#pragma unroll
                    for (int l2 = 0; l2 < 2; ++l2) {
                        float4 v = *(const float4*)(aptr[l2] + k0);
                        As[aq[l2] * 4 + 0][ar[l2]] = v.x;
                        As[aq[l2] * 4 + 1][ar[l2]] = v.y;
                        As[aq[l2] * 4 + 2][ar[l2]] = v.z;
                        As[aq[l2] * 4 + 3][ar[l2]] = v.w;
                    }
#pragma unroll
                    for (int l2 = 0; l2 < 2; ++l2) {
                        float4 v = *(const float4*)(Wt0 + (size_t)(k0 + bkk[l2]) * FOURH + n0 + bq[l2] * 4);
                        *(float4*)&Bs[bkk[l2]][bq[l2] * 4] = v;
                    }
                    __syncthreads();
#pragma unroll
                    for (int kk = 0; kk < BK; ++kk) {
                        float a[8], bb[4];
                        *(float4*)&a[0] = *(const float4*)&As[kk][tm * 4];
                        *(float4*)&a[4] = *(const float4*)&As[kk][64 + tm * 4];
                        *(float4*)&bb[0] = *(const float4*)&Bs[kk][tn * 4];
#pragma unroll
                        for (int rh = 0; rh < 2; ++rh)
#pragma unroll
                            for (int i = 0; i < 4; ++i)
#pragma unroll
                                for (int jj = 0; jj < 4; ++jj)
                                    acc[rh][i][jj] = fmaf(a[rh * 4 + i], bb[jj], acc[rh][i][jj]);
                    }
                }
#pragma unroll
                for (int rh = 0; rh < 2; ++rh)
#pragma unroll
                    for (int i = 0; i < 4; ++i) {
                        int rl = by * BM + rh * 64 + tm * 4 + i;
                        int b = rl >> 4;
                        int slot = (idx & 15) * 16 + (rl & 15);
                        float* gp = gring + ((size_t)slot * BATCH + b) * FOURH + n0 + tn * 4;
                        float4 o = make_float4(acc[rh][i][0] + bvg.x, acc[rh][i][1] + bvg.y,
                                               acc[rh][i][2] + bvg.z, acc[rh][i][3] + bvg.w);
                        *(float4*)gp = o;
                    }
                __syncthreads();
                if (tid == 0) {
                    __threadfence();
                    __hip_atomic_fetch_add(&chunkDone[idx], 1, __ATOMIC_RELEASE,
                                           __HIP_MEMORY_SCOPE_AGENT);
                }
            }

            int m = idx - D1;
            if (m >= 0 && m < NCHUNK) {
                // ---- G1 chunk m (fp16 MFMA: b1 + h1@Wih1^T, bit-identical) ----
                if (tid == 0) {
                    while (__hip_atomic_load(&prodF[by], __ATOMIC_RELAXED,
                                             __HIP_MEMORY_SCOPE_AGENT) < 16 * (m + 1))
                        __builtin_amdgcn_s_sleep(4);
                    if (m >= 16) {
                        while (__hip_atomic_load(&consF[by], __ATOMIC_RELAXED,
                                                 __HIP_MEMORY_SCOPE_AGENT) < 16 * (m - 15))
                            __builtin_amdgcn_s_sleep(4);
                    }
                    (void)__hip_atomic_load(&prodF[by], __ATOMIC_ACQUIRE,
                                            __HIP_MEMORY_SCOPE_AGENT);
                }
                __syncthreads();

                const int t0 = m * 16;
                half8 Af[4];
                const _Float16* ap = h1p + ((size_t)(t0 + li) * BATCH + gb1) * H + q * 8;
#pragma unroll
                for (int kf = 0; kf < 4; ++kf)
                    Af[kf] = *(const half8*)(ap + kf * 32);

                f32x4 acc1[8];
#pragma unroll
                for (int ct = 0; ct < 8; ++ct) {
                    acc1[ct][0] = bv1g[ct]; acc1[ct][1] = bv1g[ct];
                    acc1[ct][2] = bv1g[ct]; acc1[ct][3] = bv1g[ct];
                }
#pragma unroll
                for (int ct = 0; ct < 8; ++ct) {
                    const _Float16* wp = wt1h + (size_t)(n0 + ct * 16 + li) * H + q * 8;
#pragma unroll
                    for (int kf = 0; kf < 4; ++kf) {
                        half8 Bfr = *(const half8*)(wp + kf * 32);
                        acc1[ct] = __builtin_amdgcn_mfma_f32_16x16x32_f16(Af[kf], Bfr, acc1[ct], 0, 0, 0);
                    }
                }
                const int srow = (t0 & 255) + q * 4;
#pragma unroll
                for (int ct = 0; ct < 8; ++ct)
#pragma unroll
                    for (int i = 0; i < 4; ++i)
                        g1r[((size_t)(srow + i) * BATCH + gb1) * FOURH + n0 + ct * 16 + li] = acc1[ct][i];
                __syncthreads();
                if (tid == 0) {
                    __threadfence();
                    __hip_atomic_fetch_add(&g1Done[m], 1, __ATOMIC_RELEASE,
                                           __HIP_MEMORY_SCOPE_AGENT);
                }
            }
        }
        return;
    }

    // ================= scan blocks =================
    const int w  = tid >> 6;
    const int l  = tid & 63;
    const int li = l & 15;
    const int q  = l >> 4;
    const int u  = 16 * w + li;                 // owned hidden unit (C col)
    const int b0 = q * 2;                       // local batch for C-row r=0
    const int ab = ((li >> 2) * 2) + (li & 1);  // A-row -> local batch (dup map)

#define WAIT_FLAG(ptr, tgtv)                                                   \
    do {                                                                       \
        if (tid == 0) {                                                        \
            while (__hip_atomic_load((ptr), __ATOMIC_RELAXED,                  \
                                     __HIP_MEMORY_SCOPE_AGENT) < (tgtv))       \
                __builtin_amdgcn_s_sleep(4);                                   \
            (void)__hip_atomic_load((ptr), __ATOMIC_ACQUIRE,                   \
                                    __HIP_MEMORY_SCOPE_AGENT);                 \
        }                                                                      \
        __syncthreads();                                                       \
    } while (0)

// Shared scan-step skeleton: G-source ring slot (S+4)&255 prefetched into GR,
// 16 MFMAs (4 gates x K=128 recurrent), activations, h handoff via LDS.
#define SCAN_STEP(S, PB, GR, GBASE, BOFF0, BOFF1, BFARR, STORE_STMT)              \
    {                                                                             \
        half8 Afr[4];                                                             \
        _Pragma("unroll")                                                         \
        for (int kf = 0; kf < 4; ++kf)                                            \
            Afr[kf] = *(const half8*)&hbuf[PB][ab][kf * 32 + q * 8];              \
        f32x4 acc[4];                                                             \
        _Pragma("unroll")                                                         \
        for (int tl = 0; tl < 4; ++tl) {                                          \
            acc[tl][0] = GR[tl * 2 + 0]; acc[tl][1] = GR[tl * 2 + 1];             \
            acc[tl][2] = 0.f;            acc[tl][3] = 0.f;                        \
        }                                                                         \
        {                                                                         \
            const float* gp_ = (GBASE) + (size_t)(((S) + 4) & (RSLOT - 1)) * GSTRIDE; \
            _Pragma("unroll")                                                     \
            for (int tl = 0; tl < 4; ++tl) {                                      \
                GR[tl * 2 + 0] = gp_[(BOFF0) + tl * H];                           \
                GR[tl * 2 + 1] = gp_[(BOFF1) + tl * H];                           \
            }                                                                     \
        }                                                                         \
        _Pragma("unroll")                                                         \
        for (int kf = 0; kf < 4; ++kf)                                            \
            _Pragma("unroll")                                                     \
            for (int tl = 0; tl < 4; ++tl)                                        \
                acc[tl] = __builtin_amdgcn_mfma_f32_16x16x32_f16(Afr[kf], BFARR[tl][kf], acc[tl], 0, 0, 0); \
        {                                                                         \
            float ig = sigmoid_f(acc[0][0]);                                      \
            float fg = sigmoid_f(acc[1][0]);                                      \
            float gg = tanh_f(acc[2][0]);                                         \
            float og = sigmoid_f(acc[3][0]);                                      \
            c0 = fmaf(fg, c0, ig * gg);                                           \
            h0 = og * tanh_f(c0);                                                 \
            float ig1 = sigmoid_f(acc[0][1]);                                     \
            float fg1 = sigmoid_f(acc[1][1]);                                     \
            float gg1 = tanh_f(acc[2][1]);                                        \
            float og1 = sigmoid_f(acc[3][1]);                                     \
            c1 = fmaf(fg1, c1, ig1 * gg1);                                        \
            h1v = og1 * tanh_f(c1);                                               \
        }                                                                         \
        hbuf[PB ^ 1][b0][u]     = (_Float16)h0;                                   \
        hbuf[PB ^ 1][b0 + 1][u] = (_Float16)h1v;                                  \
        STORE_STMT                                                                \
        LDS_BARRIER();                                                            \
    }

    if (blockIdx.x < 8) {
        // ================= producer: layer 0 =================
        const int g = blockIdx.x;

        half8 Bf[4][4];
#pragma unroll
        for (int tl = 0; tl < 4; ++tl)
#pragma unroll
            for (int kf = 0; kf < 4; ++kf) {
                const float* wp = Whh0 + (size_t)(tl * 128 + u) * H + kf * 32 + q * 8;
                float4 v0 = *(const float4*)wp;
                float4 v1 = *(const float4*)(wp + 4);
                half8 b;
                b[0] = (_Float16)v0.x; b[1] = (_Float16)v0.y;
                b[2] = (_Float16)v0.z; b[3] = (_Float16)v0.w;
                b[4] = (_Float16)v1.x; b[5] = (_Float16)v1.y;
                b[6] = (_Float16)v1.z; b[7] = (_Float16)v1.w;
                Bf[tl][kf] = b;
            }

        float c0 = 0.f, c1 = 0.f, h0 = 0.f, h1v = 0.f;
        hbuf[0][b0][u]     = (_Float16)0.f;
        hbuf[0][b0 + 1][u] = (_Float16)0.f;

        const int boff0 = (8 * g + b0) * FOURH + u;
        const int boff1 = boff0 + FOURH;

        WAIT_FLAG(&chunkDone[0], 32);     // first G0 chunk ready (orders hbuf init too)

        float Ga[8], Gb[8], Gc[8], Gd[8];
#pragma unroll
        for (int tl = 0; tl < 4; ++tl) {
            Ga[tl * 2 + 0] = gring[(size_t)0 * GSTRIDE + boff0 + tl * H];
            Ga[tl * 2 + 1] = gring[(size_t)0 * GSTRIDE + boff1 + tl * H];
            Gb[tl * 2 + 0] = gring[(size_t)1 * GSTRIDE + boff0 + tl * H];
            Gb[tl * 2 + 1] = gring[(size_t)1 * GSTRIDE + boff1 + tl * H];
            Gc[tl * 2 + 0] = gring[(size_t)2 * GSTRIDE + boff0 + tl * H];
            Gc[tl * 2 + 1] = gring[(size_t)2 * GSTRIDE + boff1 + tl * H];
            Gd[tl * 2 + 0] = gring[(size_t)3 * GSTRIDE + boff0 + tl * H];
            Gd[tl * 2 + 1] = gring[(size_t)3 * GSTRIDE + boff1 + tl * H];
        }

        _Float16* php = h1p + (size_t)(8 * g + b0) * H + u;   // +step*8192

#define P_STORE { php[0] = (_Float16)h0; php[128] = (_Float16)h1v; php += BATCH * H; }

        for (int s4 = 0; s4 < TC; s4 += 4) {
            if ((s4 & 15) == 0) {
                int k = (s4 >> 4) + 1;               // prefetch spills into next chunk
                if (k > NCHUNK - 1) k = NCHUNK - 1;
                WAIT_FLAG(&chunkDone[k], 32);
            }
            SCAN_STEP(s4 + 0, 0, Ga, gring, boff0, boff1, Bf, P_STORE)
            SCAN_STEP(s4 + 1, 1, Gb, gring, boff0, boff1, Bf, P_STORE)
            SCAN_STEP(s4 + 2, 0, Gc, gring, boff0, boff1, Bf, P_STORE)
            SCAN_STEP(s4 + 3, 1, Gd, gring, boff0, boff1, Bf, P_STORE)
            if ((s4 & 31) == 28) {
                __threadfence();            // make h1p stores device-visible
                __syncthreads();            // all waves fenced before flag
                if (tid == 0)
                    __hip_atomic_store(&prodF[g], s4 + 4, __ATOMIC_RELEASE,
                                       __HIP_MEMORY_SCOPE_AGENT);
            }
        }
#undef P_STORE
    } else {
        // ================= consumer: layer 1 (recurrent only) =================
        const int g = blockIdx.x - 8;

        half8 Bf[4][4];   // Whh1 fragments only
#pragma unroll
        for (int tl = 0; tl < 4; ++tl)
#pragma unroll
            for (int kf = 0; kf < 4; ++kf) {
                const float* wp = Whh1 + (size_t)(tl * 128 + u) * H + kf * 32 + q * 8;
                float4 v0 = *(const float4*)wp;
                float4 v1 = *(const float4*)(wp + 4);
                half8 b;
                b[0] = (_Float16)v0.x; b[1] = (_Float16)v0.y;
                b[2] = (_Float16)v0.z; b[3] = (_Float16)v0.w;
                b[4] = (_Float16)v1.x; b[5] = (_Float16)v1.y;
                b[6] = (_Float16)v1.z; b[7] = (_Float16)v1.w;
                Bf[tl][kf] = b;
            }

        float c0 = 0.f, c1 = 0.f, h0, h1v;
        hbuf[0][b0][u]     = (_Float16)0.f;
        hbuf[0][b0 + 1][u] = (_Float16)0.f;

        const int boff0 = (8 * g + b0) * FOURH + u;
        const int boff1 = boff0 + FOURH;
        float* op0 = out + (size_t)(8 * g + b0) * SEQ * H + u;      // +step*H
        float* op1 = out + (size_t)(8 * g + b0 + 1) * SEQ * H + u;

        WAIT_FLAG(&g1Done[0], 32);        // first G1 chunk ready (orders hbuf init)

        float Ga[8], Gb[8], Gc[8], Gd[8];
#pragma unroll
        for (int tl = 0; tl < 4; ++tl) {
            Ga[tl * 2 + 0] = g1r[(size_t)0 * GSTRIDE + boff0 + tl * H];
            Ga[tl * 2 + 1] = g1r[(size_t)0 * GSTRIDE + boff1 + tl * H];
            Gb[tl * 2 + 0] = g1r[(size_t)1 * GSTRIDE + boff0 + tl * H];
            Gb[tl * 2 + 1] = g1r[(size_t)1 * GSTRIDE + boff1 + tl * H];
            Gc[tl * 2 + 0] = g1r[(size_t)2 * GSTRIDE + boff0 + tl * H];
            Gc[tl * 2 + 1] = g1r[(size_t)2 * GSTRIDE + boff1 + tl * H];
            Gd[tl * 2 + 0] = g1r[(size_t)3 * GSTRIDE + boff0 + tl * H];
            Gd[tl * 2 + 1] = g1r[(size_t)3 * GSTRIDE + boff1 + tl * H];
        }

#define C_STORE { op0[0] = h0; op1[0] = h1v; op0 += H; op1 += H; }

        for (int s4 = 0; s4 < TC; s4 += 4) {
            if ((s4 & 15) == 0) {
                int k = (s4 >> 4) + 1;
                if (k > NCHUNK - 1) k = NCHUNK - 1;
                WAIT_FLAG(&g1Done[k], 32);
            }
            SCAN_STEP(s4 + 0, 0, Ga, g1r, boff0, boff1, Bf, C_STORE)
            SCAN_STEP(s4 + 1, 1, Gb, g1r, boff0, boff1, Bf, C_STORE)
            SCAN_STEP(s4 + 2, 0, Gc, g1r, boff0, boff1, Bf, C_STORE)
            SCAN_STEP(s4 + 3, 1, Gd, g1r, boff0, boff1, Bf, C_STORE)
            if ((s4 & 31) == 28) {
                if (tid == 0)
                    __hip_atomic_store(&consF[g], s4 + 4, __ATOMIC_RELEASE,
                                       __HIP_MEMORY_SCOPE_AGENT);
            }
        }
#undef C_STORE
    }
#undef WAIT_FLAG
#undef SCAN_STEP
}

// ---------------- launch ----------------
extern "C" void kernel_launch(void* const* d_in, const int* in_sizes, int n_in,
                              void* d_out, int out_size, void* d_ws, size_t ws_size,
                              hipStream_t stream) {
    const float* x    = (const float*)d_in[0];
    const float* Wih0 = (const float*)d_in[1];
    const float* Whh0 = (const float*)d_in[2];
    const float* bih0 = (const float*)d_in[3];
    const float* bhh0 = (const float*)d_in[4];
    const float* Wih1 = (const float*)d_in[5];
    const float* Whh1 = (const float*)d_in[6];
    const float* bih1 = (const float*)d_in[7];
    const float* bhh1 = (const float*)d_in[8];
    float* out = (float*)d_out;

    char* ws = (char*)d_ws;
    size_t off = 0;
    auto carve = [&](size_t bytes) -> char* {
        char* p = ws + off;
        off += (bytes + 255) & ~(size_t)255;
        return p;
    };

    float*     Wt0   = (float*)carve(256 * 512 * 4);
    float*     b0v   = (float*)carve(512 * 4);
    float*     b1v   = (float*)carve(512 * 4);
    _Float16*  wt1h  = (_Float16*)carve(65536 * 2);
    _Float16*  h1p   = (_Float16*)carve((size_t)SEQ * BATCH * H * 2);    // 33.6 MB
    int*       flags = (int*)carve(272 * 4);
    float*     gring = (float*)carve((size_t)RSLOT * GSTRIDE * 4);       // 33.6 MB
    float*     g1r   = (float*)carve((size_t)RSLOT * GSTRIDE * 4);       // 33.6 MB

    prep_kernel<<<774, 256, 0, stream>>>(Wih0, bih0, bhh0, bih1, bhh1, Wih1,
                                         Wt0, b0v, b1v, wt1h, flags);

    // single persistent kernel: gemm workers + 2-layer pipelined scan
    lstm_fused_kernel<<<240, 512, 0, stream>>>(x, Wt0, b0v, gring,
                                               Whh0, wt1h, Whh1, b1v,
                                               h1p, g1r, out, flags);
}